// Round 6
// baseline (86.246 us; speedup 1.0000x reference)
//
#include <hip/hip_runtime.h>

// Problem constants (match reference)
#define TB 8
#define TT 400
#define TS 40
#define TV 512
#define SU (TS + 1)          // 41
#define NROWS (TB * TT * SU) // 131200
#define KCH 8                // t-steps per chunk
#define NCH (TT / KCH)       // 50 chunks
#define RPC (TB * KCH * SU)  // rows per chunk          = 2624
#define RPBC (KCH * SU)      // rows per (batch, chunk) = 328
#define SENT 0xAAAAAAAAu     // poison pattern = sentinel (unreachable as lp value)
#define NEG_INF (-1.0e30f)
#define INV_LN2 1.44269504088896341f
#define LN2 0.69314718055994531f

// VALU whole-wave shift-up-by-1 (DPP wave_shr:1); lane 0 sources 0 (harmless).
__device__ __forceinline__ float wave_shr1(float x) {
    return __int_as_float(
        __builtin_amdgcn_update_dpp(0, __float_as_int(x), 0x138, 0xf, 0xf, true));
}

// Fused producer/consumer kernel, data-as-flag sync (no counters/atomics).
//  blockIdx < TB : consumer — alpha recursion for batch b (1 wave).
//  else          : producer — per-row log-sum-exp, chunk-major order.
// lp buffers are pre-poisoned to 0xAA per replay; producers write final values
// with agent-scope stores (visible at coherence point); consumers poll values
// with agent-scope loads (bypass L1/L2 — a cached poison line would deadlock).
// Each 4B value is its own ready-flag: a load returns poison or the final
// value, nothing else. Producers have ZERO sync overhead (no drain/barrier).
__global__ __launch_bounds__(256) void fused_kernel(
    const float* __restrict__ acts, const int* __restrict__ labels,
    const int* __restrict__ input_lengths, const int* __restrict__ label_lengths,
    float* __restrict__ out,
    float* lp_blank, float* lp_label)
{
    if (blockIdx.x >= TB) {
        // ---------------- producer: row log-sum-exp ----------------
        const int wave = threadIdx.x >> 6;
        const int lane = threadIdx.x & 63;
        const int w = (blockIdx.x - TB) * 4 + wave;   // [0, NROWS)
        // chunk-major decode: (c, b, kt, u) — all batches progress together
        const int c  = w / RPC;
        const int r  = w - c * RPC;
        const int b  = r / RPBC;
        const int r2 = r - b * RPBC;
        const int kt = r2 / SU;
        const int u  = r2 - kt * SU;
        const int t  = c * KCH + kt;
        const int bt = b * TT + t;
        const int row = bt * SU + u;

        const float* rp = acts + (size_t)row * TV;
        float4 av = *(const float4*)(rp + lane * 8);
        float4 bv = *(const float4*)(rp + lane * 8 + 4);

        float m = fmaxf(fmaxf(fmaxf(av.x, av.y), fmaxf(av.z, av.w)),
                        fmaxf(fmaxf(bv.x, bv.y), fmaxf(bv.z, bv.w)));
#pragma unroll
        for (int off = 1; off < 64; off <<= 1) m = fmaxf(m, __shfl_xor(m, off));

        float s = __expf(av.x-m)+__expf(av.y-m)+__expf(av.z-m)+__expf(av.w-m)
                + __expf(bv.x-m)+__expf(bv.y-m)+__expf(bv.z-m)+__expf(bv.w-m);
#pragma unroll
        for (int off = 1; off < 64; off <<= 1) s += __shfl_xor(s, off);

        const float logZ = m + logf(s);

        if (lane == 0) {
            // agent-scope stores: land at the coherence point, each value is
            // its own ready flag. log2 domain. No drain/barrier/atomic after.
            __hip_atomic_store(&lp_blank[row], (av.x - logZ) * INV_LN2,
                               __ATOMIC_RELAXED, __HIP_MEMORY_SCOPE_AGENT);
            if (u < TS) {
                const int col = labels[b * TS + u];
                __hip_atomic_store(&lp_label[bt * TS + u],
                                   (rp[col] - logZ) * INV_LN2,
                                   __ATOMIC_RELAXED, __HIP_MEMORY_SCOPE_AGENT);
            }
        }
        return;
    }

    // ---------------- consumer: alpha recursion (1 wave) ----------------
    if (threadIdx.x >= 64) return;
    const int b = blockIdx.x;
    const int u = threadIdx.x;

    const int inlen  = input_lengths[b];
    const int lablen = label_lengths[b];
    const int c_sel  = (inlen - 1) / KCH;   // uniform scalar select for 'saved'
    const int k_sel  = (inlen - 1) % KCH;

    const int uu = (u <= TS) ? u : TS;      // clamp so dead lanes read valid mem
    const int ul = (u >= 1 && u <= TS) ? (u - 1) : 0;
    const unsigned int* pb_ptr =
        (const unsigned int*)(lp_blank + (size_t)b * TT * SU + uu);
    const unsigned int* pl_ptr =
        (const unsigned int*)(lp_label + (size_t)b * TT * TS + ul);
    const bool u_dead = (u == 0 || u > TS); // lanes where 'move' is invalid

    float alpha = (u == 0) ? 0.0f : NEG_INF;
    float saved = NEG_INF;

    unsigned int pbA[KCH], plA[KCH], pbB[KCH], plB[KCH];  // raw bits

// issue KCH*2 agent-scope loads (bypass caches), no wait
#define LOADC(PB, PL, C) { \
    _Pragma("unroll") \
    for (int k = 0; k < KCH; ++k) { \
        (PB)[k] = __hip_atomic_load(&pb_ptr[((C) * KCH + k) * SU], \
                      __ATOMIC_RELAXED, __HIP_MEMORY_SCOPE_AGENT); \
        (PL)[k] = __hip_atomic_load(&pl_ptr[((C) * KCH + k) * TS], \
                      __ATOMIC_RELAXED, __HIP_MEMORY_SCOPE_AGENT); \
    } }

// wait for the buffer's loads, verify no sentinel; retry (rare) reloads
#define CHECKC(PB, PL, C) { \
    while (true) { \
        bool ok = true; \
        _Pragma("unroll") \
        for (int k = 0; k < KCH; ++k) \
            ok = ok && ((PB)[k] != SENT) && ((PL)[k] != SENT); \
        if (__all(ok)) break; \
        __builtin_amdgcn_s_sleep(4); \
        LOADC(PB, PL, C); \
    } }

#define COMPUTE(PB, PL, C) { \
    _Pragma("unroll") \
    for (int k = 0; k < KCH; ++k) { \
        const float prev = wave_shr1(alpha); \
        const float stay = alpha + __uint_as_float((PB)[k]); \
        const float plv  = u_dead ? NEG_INF : __uint_as_float((PL)[k]); \
        const float move = prev + plv; \
        const float mx = fmaxf(stay, move); \
        const float mn = fminf(stay, move); \
        alpha = mx + __builtin_amdgcn_logf(1.0f + __builtin_amdgcn_exp2f(mn - mx)); \
        if ((C) == c_sel && k == k_sel) saved = alpha; \
    } }

    LOADC(pbA, plA, 0);
    CHECKC(pbA, plA, 0);      // startup poll: waits for chunk 0 production
    LOADC(pbB, plB, 1);
    // invariant at loop top: A = chunk c0 (valid), B = chunk c0+1 (in flight)
    for (int i = 0; i < 24; ++i) {
        const int c0 = 2 * i;
        COMPUTE(pbA, plA, c0);        // hides B's load latency
        LOADC(pbA, plA, c0 + 2);      // reuse A for c0+2
        CHECKC(pbB, plB, c0 + 1);
        COMPUTE(pbB, plB, c0 + 1);    // hides A's load latency
        LOADC(pbB, plB, c0 + 3);      // max = 49
        CHECKC(pbA, plA, c0 + 2);     // max = 48
    }
    COMPUTE(pbA, plA, NCH - 2);       // chunk 48
    CHECKC(pbB, plB, NCH - 1);
    COMPUTE(pbB, plB, NCH - 1);       // chunk 49

#undef LOADC
#undef CHECKC
#undef COMPUTE

    const float cost_alpha = __shfl(saved, lablen);
    if (u == 0) out[b] = -cost_alpha * LN2;   // back to natural log
}

extern "C" void kernel_launch(void* const* d_in, const int* in_sizes, int n_in,
                              void* d_out, int out_size, void* d_ws, size_t ws_size,
                              hipStream_t stream) {
    const float* acts          = (const float*)d_in[0];
    const int*   labels        = (const int*)d_in[1];
    const int*   input_lengths = (const int*)d_in[2];
    const int*   label_lengths = (const int*)d_in[3];
    float* out = (float*)d_out;

    float* lp_blank = (float*)d_ws;                 // NROWS floats
    float* lp_label = lp_blank + NROWS;             // TB*TT*TS floats

    // per-replay sentinel poison of the lp region (0xAA bytes = SENT words);
    // kernel-dispatch release fence makes it coherent before producers start
    hipMemsetAsync(d_ws, 0xAA, (size_t)(NROWS + TB * TT * TS) * sizeof(float),
                   stream);
    fused_kernel<<<TB + NROWS / 4, 256, 0, stream>>>(
        acts, labels, input_lengths, label_lengths, out,
        lp_blank, lp_label);
}

// Round 7
// 58.828 us; speedup vs baseline: 1.4661x; 1.4661x over previous
//
#include <hip/hip_runtime.h>

// Problem constants (match reference)
#define TB 8
#define TT 400
#define TS 40
#define TV 512
#define SU (TS + 1)          // 41
#define NROWS (TB * TT * SU) // 131200
#define NSS (TT / 4)         // 100 supersteps of 4 t-steps each
#define NEG_INF (-1.0e30f)
#define INV_LN2 1.44269504088896341f
#define LN2 0.69314718055994531f

// VALU whole-wave shift-up-by-1 (DPP wave_shr:1); lane 0 sources 0 (harmless).
__device__ __forceinline__ float wave_shr1(float x) {
    return __int_as_float(
        __builtin_amdgcn_update_dpp(0, __float_as_int(x), 0x138, 0xf, 0xf, true));
}

// base-2 logsumexp helpers (lp values live in log2 domain)
__device__ __forceinline__ float lse4(float a, float b, float c, float d) {
    float m = fmaxf(fmaxf(a, b), fmaxf(c, d));
    float s = __builtin_amdgcn_exp2f(a - m) + __builtin_amdgcn_exp2f(b - m)
            + __builtin_amdgcn_exp2f(c - m) + __builtin_amdgcn_exp2f(d - m);
    return m + __builtin_amdgcn_logf(s);
}
__device__ __forceinline__ float lse6(float a, float b, float c,
                                      float d, float e, float f) {
    float m = fmaxf(fmaxf(fmaxf(a, b), fmaxf(c, d)), fmaxf(e, f));
    float s = __builtin_amdgcn_exp2f(a - m) + __builtin_amdgcn_exp2f(b - m)
            + __builtin_amdgcn_exp2f(c - m) + __builtin_amdgcn_exp2f(d - m)
            + __builtin_amdgcn_exp2f(e - m) + __builtin_amdgcn_exp2f(f - m);
    return m + __builtin_amdgcn_logf(s);
}

// ---------------- kernel 1: per-row log-sum-exp (HBM-bound, ~40us) ----------
__global__ __launch_bounds__(256) void rowlse_kernel(
    const float* __restrict__ acts, const int* __restrict__ labels,
    float* __restrict__ lp_blank, float* __restrict__ lp_label)
{
    const int wave = threadIdx.x >> 6;
    const int lane = threadIdx.x & 63;
    const int row  = blockIdx.x * 4 + wave;   // grid*4 == NROWS exactly

    const float* rp = acts + (size_t)row * TV;
    float4 a = *(const float4*)(rp + lane * 8);
    float4 b = *(const float4*)(rp + lane * 8 + 4);

    float m = fmaxf(fmaxf(fmaxf(a.x, a.y), fmaxf(a.z, a.w)),
                    fmaxf(fmaxf(b.x, b.y), fmaxf(b.z, b.w)));
#pragma unroll
    for (int off = 1; off < 64; off <<= 1) m = fmaxf(m, __shfl_xor(m, off));

    float s = __expf(a.x - m) + __expf(a.y - m) + __expf(a.z - m) + __expf(a.w - m)
            + __expf(b.x - m) + __expf(b.y - m) + __expf(b.z - m) + __expf(b.w - m);
#pragma unroll
    for (int off = 1; off < 64; off <<= 1) s += __shfl_xor(s, off);

    const float logZ = m + logf(s);

    if (lane == 0) {
        const int u  = row % SU;
        const int bt = row / SU;
        lp_blank[row] = (a.x - logZ) * INV_LN2;          // log2 domain
        if (u < TS) {
            const int b_idx = bt / TT;
            const int col   = labels[b_idx * TS + u];
            lp_label[bt * TS + u] = (rp[col] - logZ) * INV_LN2;
        }
    }
}

// ------- kernel 2: compose 4 t-steps into 5 path weights W_j (parallel) -----
// alpha'[u] = LSE_{j=0..4}( alpha[u-j] + W_j[u] ).  16 paths enumerated:
// j moves among 4 steps, C(4,j) paths each, LSE-reduced here (off the serial
// critical path). One wave per (b, superstep); lane = u.
__global__ __launch_bounds__(256) void compose_kernel(
    const float* __restrict__ lp_blank, const float* __restrict__ lp_label,
    float* __restrict__ W)
{
    const int wv   = blockIdx.x * 4 + (threadIdx.x >> 6);  // [0, TB*NSS)
    const int lane = threadIdx.x & 63;
    const int b = wv / NSS;
    const int s = wv - b * NSS;
    const int t0 = s * 4;
    const int u  = (lane <= TS) ? lane : TS;               // clamp loads

    const float* pb = lp_blank + ((size_t)b * TT + t0) * SU + u;
    const float* pl = lp_label + ((size_t)b * TT + t0) * TS + ((u >= 1) ? u - 1 : 0);
    const float b0 = pb[0], b1 = pb[SU], b2 = pb[2 * SU], b3 = pb[3 * SU];
    const float l0 = pl[0], l1 = pl[TS], l2 = pl[2 * TS], l3 = pl[3 * TS];

    // shifted copies: *_mK = value at u-K (garbage flows only into masked W_j)
    const float bm1_0 = wave_shr1(b0), bm1_1 = wave_shr1(b1), bm1_2 = wave_shr1(b2);
    const float bm2_0 = wave_shr1(bm1_0), bm2_1 = wave_shr1(bm1_1);
    const float bm3_0 = wave_shr1(bm2_0);
    const float lm1_0 = wave_shr1(l0), lm1_1 = wave_shr1(l1), lm1_2 = wave_shr1(l2);
    const float lm2_0 = wave_shr1(lm1_0), lm2_1 = wave_shr1(lm1_1);
    const float lm3_0 = wave_shr1(lm2_0);

    const float W0 = b0 + b1 + b2 + b3;
    // j=1: move at step m
    const float W1 = lse4(l0 + b1 + b2 + b3,
                          bm1_0 + l1 + b2 + b3,
                          bm1_0 + bm1_1 + l2 + b3,
                          bm1_0 + bm1_1 + bm1_2 + l3);
    // j=2: moves at (m1<m2)
    const float W2 = lse6(lm1_0 + l1 + b2 + b3,          // (0,1)
                          lm1_0 + bm1_1 + l2 + b3,       // (0,2)
                          lm1_0 + bm1_1 + bm1_2 + l3,    // (0,3)
                          bm2_0 + lm1_1 + l2 + b3,       // (1,2)
                          bm2_0 + lm1_1 + bm1_2 + l3,    // (1,3)
                          bm2_0 + bm2_1 + lm1_2 + l3);   // (2,3)
    // j=3: stay at step m
    const float W3 = lse4(bm3_0 + lm2_1 + lm1_2 + l3,    // stay@0
                          lm2_0 + bm2_1 + lm1_2 + l3,    // stay@1
                          lm2_0 + lm1_1 + bm1_2 + l3,    // stay@2
                          lm2_0 + lm1_1 + l2 + b3);      // stay@3
    const float W4 = lm3_0 + lm2_1 + lm1_2 + l3;

    if (lane <= TS) {
        float* wp = W + (((size_t)b * NSS + s) * 5) * SU + lane;
        wp[0 * SU] = W0;
        wp[1 * SU] = (lane >= 1) ? W1 : NEG_INF;
        wp[2 * SU] = (lane >= 2) ? W2 : NEG_INF;
        wp[3 * SU] = (lane >= 3) ? W3 : NEG_INF;
        wp[4 * SU] = (lane >= 4) ? W4 : NEG_INF;
    }
}

// ---------------- kernel 3: serial scan, 100 supersteps (8 waves) -----------
__global__ __launch_bounds__(64) void scan_kernel(
    const float* __restrict__ W,
    const float* __restrict__ lp_blank, const float* __restrict__ lp_label,
    const int* __restrict__ input_lengths, const int* __restrict__ label_lengths,
    float* __restrict__ out)
{
    const int b = blockIdx.x;
    const int u = threadIdx.x;

    const int inlen  = input_lengths[b];
    const int lablen = label_lengths[b];
    const int rr     = inlen & 3;
    const int s_part = inlen >> 2;                       // tail-singles superstep
    const int s_cap  = (rr == 0) ? (inlen >> 2) - 1 : -1; // capture-after superstep

    const int uu = (u <= TS) ? u : TS;
    const int ul = (u >= 1 && u <= TS) ? (u - 1) : 0;
    const bool u_dead = (u == 0 || u > TS);
    const float* wbase = W + ((size_t)b * NSS * 5) * SU + uu;

    float alpha = (u == 0) ? 0.0f : NEG_INF;
    float saved = NEG_INF;

    float wA[20], wB[20];   // 4 supersteps x 5 coeffs, double-buffered

#define LOADG(BUF, G) { \
    _Pragma("unroll") \
    for (int ss = 0; ss < 4; ++ss) { \
        _Pragma("unroll") \
        for (int j = 0; j < 5; ++j) \
            (BUF)[ss * 5 + j] = wbase[((size_t)(((G) * 4 + ss) * 5 + j)) * SU]; \
    } }

#define COMPG(BUF, G) { \
    _Pragma("unroll") \
    for (int ss = 0; ss < 4; ++ss) { \
        const int s = (G) * 4 + ss; \
        if (rr && s == s_part) { /* rare general-length tail: r single steps */ \
            float a2 = alpha; \
            _Pragma("unroll") \
            for (int q = 0; q < 3; ++q) { \
                if (q < rr) { \
                    const int t = 4 * s_part + q; \
                    const float pb = lp_blank[((size_t)b * TT + t) * SU + uu]; \
                    float pl = lp_label[((size_t)b * TT + t) * TS + ul]; \
                    pl = u_dead ? NEG_INF : pl; \
                    const float prev = wave_shr1(a2); \
                    const float stay = a2 + pb; \
                    const float move = prev + pl; \
                    const float mx = fmaxf(stay, move); \
                    const float mn = fminf(stay, move); \
                    a2 = mx + __builtin_amdgcn_logf(1.0f + __builtin_amdgcn_exp2f(mn - mx)); \
                } \
            } \
            saved = a2; \
        } \
        const float s1 = wave_shr1(alpha); \
        const float s2 = wave_shr1(s1); \
        const float s3 = wave_shr1(s2); \
        const float s4 = wave_shr1(s3); \
        const float T0 = alpha + (BUF)[ss * 5 + 0]; \
        const float T1 = s1 + (BUF)[ss * 5 + 1]; \
        const float T2 = s2 + (BUF)[ss * 5 + 2]; \
        const float T3 = s3 + (BUF)[ss * 5 + 3]; \
        const float T4 = s4 + (BUF)[ss * 5 + 4]; \
        const float M = fmaxf(fmaxf(T0, T1), fmaxf(fmaxf(T2, T3), T4)); \
        const float sm = __builtin_amdgcn_exp2f(T0 - M) + __builtin_amdgcn_exp2f(T1 - M) \
                       + __builtin_amdgcn_exp2f(T2 - M) + __builtin_amdgcn_exp2f(T3 - M) \
                       + __builtin_amdgcn_exp2f(T4 - M); \
        alpha = M + __builtin_amdgcn_logf(sm); \
        if (s == s_cap) saved = alpha; \
    } }

    LOADG(wA, 0);
    // 25 groups of 4 supersteps: 12 double-iterations + tail (R3's shape)
    for (int i = 0; i < 12; ++i) {
        const int g0 = 2 * i;
        LOADG(wB, g0 + 1);
        COMPG(wA, g0);
        LOADG(wA, g0 + 2);
        COMPG(wB, g0 + 1);
    }
    COMPG(wA, 24);

#undef LOADG
#undef COMPG

    const float cost_alpha = __shfl(saved, lablen);
    if (u == 0) out[b] = -cost_alpha * LN2;   // back to natural log
}

extern "C" void kernel_launch(void* const* d_in, const int* in_sizes, int n_in,
                              void* d_out, int out_size, void* d_ws, size_t ws_size,
                              hipStream_t stream) {
    const float* acts          = (const float*)d_in[0];
    const int*   labels        = (const int*)d_in[1];
    const int*   input_lengths = (const int*)d_in[2];
    const int*   label_lengths = (const int*)d_in[3];
    float* out = (float*)d_out;

    float* lp_blank = (float*)d_ws;                          // NROWS floats
    float* lp_label = lp_blank + NROWS;                      // TB*TT*TS floats
    float* W        = lp_label + (size_t)TB * TT * TS;       // TB*NSS*5*SU floats

    rowlse_kernel<<<NROWS / 4, 256, 0, stream>>>(acts, labels, lp_blank, lp_label);
    compose_kernel<<<TB * NSS / 4, 256, 0, stream>>>(lp_blank, lp_label, W);
    scan_kernel<<<TB, 64, 0, stream>>>(W, lp_blank, lp_label,
                                       input_lengths, label_lengths, out);
}

// Round 8
// 56.582 us; speedup vs baseline: 1.5243x; 1.0397x over previous
//
#include <hip/hip_runtime.h>

// Problem constants (match reference)
#define TB 8
#define TT 400
#define TS 40
#define TV 512
#define SU (TS + 1)          // 41
#define NROWS (TB * TT * SU) // 131200
#define SS 8                 // t-steps per superstep
#define NSS (TT / SS)        // 50 supersteps
#define NW (SS + 1)          // 9 path weights per superstep (j = 0..8)
#define GRP 5                // supersteps per scan prefetch group
#define NGRP (NSS / GRP)     // 10 groups
#define NEG_INF (-1.0e30f)
#define INV_LN2 1.44269504088896341f
#define LN2 0.69314718055994531f

// VALU whole-wave shift-up-by-1 (DPP wave_shr:1); lane 0 sources 0 (harmless).
__device__ __forceinline__ float wave_shr1(float x) {
    return __int_as_float(
        __builtin_amdgcn_update_dpp(0, __float_as_int(x), 0x138, 0xf, 0xf, true));
}

// base-2 logaddexp (lp values live in log2 domain)
__device__ __forceinline__ float lse2(float a, float c) {
    const float mx = fmaxf(a, c), mn = fminf(a, c);
    return mx + __builtin_amdgcn_logf(1.0f + __builtin_amdgcn_exp2f(mn - mx));
}

// ---------------- kernel 1: per-row log-sum-exp (HBM-bound, ~40us) ----------
__global__ __launch_bounds__(256) void rowlse_kernel(
    const float* __restrict__ acts, const int* __restrict__ labels,
    float* __restrict__ lp_blank, float* __restrict__ lp_label)
{
    const int wave = threadIdx.x >> 6;
    const int lane = threadIdx.x & 63;
    const int row  = blockIdx.x * 4 + wave;   // grid*4 == NROWS exactly

    const float* rp = acts + (size_t)row * TV;
    float4 a = *(const float4*)(rp + lane * 8);
    float4 b = *(const float4*)(rp + lane * 8 + 4);

    float m = fmaxf(fmaxf(fmaxf(a.x, a.y), fmaxf(a.z, a.w)),
                    fmaxf(fmaxf(b.x, b.y), fmaxf(b.z, b.w)));
#pragma unroll
    for (int off = 1; off < 64; off <<= 1) m = fmaxf(m, __shfl_xor(m, off));

    float s = __expf(a.x - m) + __expf(a.y - m) + __expf(a.z - m) + __expf(a.w - m)
            + __expf(b.x - m) + __expf(b.y - m) + __expf(b.z - m) + __expf(b.w - m);
#pragma unroll
    for (int off = 1; off < 64; off <<= 1) s += __shfl_xor(s, off);

    const float logZ = m + logf(s);

    if (lane == 0) {
        const int u  = row % SU;
        const int bt = row / SU;
        lp_blank[row] = (a.x - logZ) * INV_LN2;          // log2 domain
        if (u < TS) {
            const int b_idx = bt / TT;
            const int col   = labels[b_idx * TS + u];
            lp_label[bt * TS + u] = (rp[col] - logZ) * INV_LN2;
        }
    }
}

// ------- kernel 2: compose 8 t-steps into 9 path weights W_j (parallel) -----
// In-register DP over the 8 steps (this IS the alpha recurrence started from
// a delta): E[j] <- LSE2( E[j]+b_m , shr1(E[j-1])+l_m ), j descending.
// W_j[u] = weight of all 8-step paths ending at u with j moves.
// One wave per (b, superstep); lane = u.  36 fully-unrolled LSE2 per wave.
__global__ __launch_bounds__(256) void compose_kernel(
    const float* __restrict__ lp_blank, const float* __restrict__ lp_label,
    float* __restrict__ W)
{
    const int wv   = blockIdx.x * 4 + (threadIdx.x >> 6);  // [0, TB*NSS)
    const int lane = threadIdx.x & 63;
    const int b  = wv / NSS;
    const int s  = wv - b * NSS;
    const int t0 = s * SS;
    const int uu = (lane <= TS) ? lane : TS;               // clamp loads
    const bool have_l = (lane >= 1 && lane <= TS);

    const float* pb = lp_blank + ((size_t)b * TT + t0) * SU + uu;
    const float* pl = lp_label + ((size_t)b * TT + t0) * TS + (have_l ? lane - 1 : 0);

    float bm[SS], lm[SS];
#pragma unroll
    for (int m = 0; m < SS; ++m) {
        bm[m] = pb[m * SU];
        float lv = pl[m * TS];
        lm[m] = have_l ? lv : NEG_INF;   // u=0 / u>TS: move-into-u invalid
    }

    float E[NW];
    E[0] = 0.0f;
#pragma unroll
    for (int j = 1; j < NW; ++j) E[j] = NEG_INF;

#pragma unroll
    for (int m = 0; m < SS; ++m) {
#pragma unroll
        for (int jj = 0; jj < NW - 1; ++jj) {
            const int j = (NW - 1) - jj;         // j = 8..1 (compile-time)
            if (j <= m + 1)
                E[j] = lse2(E[j] + bm[m], wave_shr1(E[j - 1]) + lm[m]);
        }
        E[0] += bm[m];
    }

    if (lane <= TS) {
        float* wp = W + (((size_t)b * NSS + s) * NW) * SU + lane;
#pragma unroll
        for (int j = 0; j < NW; ++j)
            wp[j * SU] = (lane >= j) ? E[j] : NEG_INF;   // belt-and-braces mask
    }
}

// ---------------- kernel 3: serial scan, 50 supersteps (8 waves) ------------
__global__ __launch_bounds__(64) void scan_kernel(
    const float* __restrict__ W,
    const float* __restrict__ lp_blank, const float* __restrict__ lp_label,
    const int* __restrict__ input_lengths, const int* __restrict__ label_lengths,
    float* __restrict__ out)
{
    const int b = blockIdx.x;
    const int u = threadIdx.x;

    const int inlen  = input_lengths[b];
    const int lablen = label_lengths[b];
    const int rr     = inlen & (SS - 1);
    const int s_part = inlen >> 3;                        // tail-singles superstep
    const int s_cap  = (rr == 0) ? s_part - 1 : -1;       // capture-after superstep

    const int uu = (u <= TS) ? u : TS;
    const int ul = (u >= 1 && u <= TS) ? (u - 1) : 0;
    const bool u_dead = (u == 0 || u > TS);
    const float* wbase = W + ((size_t)b * NSS * NW) * SU + uu;

    float alpha = (u == 0) ? 0.0f : NEG_INF;
    float saved = NEG_INF;

    float wA[GRP * NW], wB[GRP * NW];   // 5 supersteps x 9 coeffs, double-buffered

#define LOADG(BUF, G) { \
    _Pragma("unroll") \
    for (int ss = 0; ss < GRP; ++ss) { \
        _Pragma("unroll") \
        for (int j = 0; j < NW; ++j) \
            (BUF)[ss * NW + j] = wbase[((size_t)((((G) * GRP + ss) * NW) + j)) * SU]; \
    } }

#define COMPG(BUF, G) { \
    _Pragma("unroll") \
    for (int ss = 0; ss < GRP; ++ss) { \
        const int s = (G) * GRP + ss; \
        if (rr && s == s_part) { /* rare general-length tail: rr single steps */ \
            float a2 = alpha; \
            _Pragma("unroll") \
            for (int q = 0; q < SS - 1; ++q) { \
                if (q < rr) { \
                    const int t = SS * s_part + q; \
                    const float pbv = lp_blank[((size_t)b * TT + t) * SU + uu]; \
                    float plv = lp_label[((size_t)b * TT + t) * TS + ul]; \
                    plv = u_dead ? NEG_INF : plv; \
                    const float prev = wave_shr1(a2); \
                    a2 = lse2(a2 + pbv, prev + plv); \
                } \
            } \
            saved = a2; \
        } \
        const float s1 = wave_shr1(alpha), s2 = wave_shr1(s1); \
        const float s3 = wave_shr1(s2),    s4 = wave_shr1(s3); \
        const float s5 = wave_shr1(s4),    s6 = wave_shr1(s5); \
        const float s7 = wave_shr1(s6),    s8 = wave_shr1(s7); \
        const float T0 = alpha + (BUF)[ss * NW + 0]; \
        const float T1 = s1 + (BUF)[ss * NW + 1]; \
        const float T2 = s2 + (BUF)[ss * NW + 2]; \
        const float T3 = s3 + (BUF)[ss * NW + 3]; \
        const float T4 = s4 + (BUF)[ss * NW + 4]; \
        const float T5 = s5 + (BUF)[ss * NW + 5]; \
        const float T6 = s6 + (BUF)[ss * NW + 6]; \
        const float T7 = s7 + (BUF)[ss * NW + 7]; \
        const float T8 = s8 + (BUF)[ss * NW + 8]; \
        const float M = fmaxf(fmaxf(fmaxf(fmaxf(T0, T1), fmaxf(T2, T3)), \
                                    fmaxf(fmaxf(T4, T5), fmaxf(T6, T7))), T8); \
        const float sm = ((__builtin_amdgcn_exp2f(T0 - M) + __builtin_amdgcn_exp2f(T1 - M)) \
                       +  (__builtin_amdgcn_exp2f(T2 - M) + __builtin_amdgcn_exp2f(T3 - M))) \
                       + ((__builtin_amdgcn_exp2f(T4 - M) + __builtin_amdgcn_exp2f(T5 - M)) \
                       +  (__builtin_amdgcn_exp2f(T6 - M) + __builtin_amdgcn_exp2f(T7 - M))) \
                       +   __builtin_amdgcn_exp2f(T8 - M); \
        alpha = M + __builtin_amdgcn_logf(sm); \
        if (s == s_cap) saved = alpha; \
    } }

    LOADG(wA, 0);
    // 10 groups of 5 supersteps: 4 double-iterations + explicit tail
    for (int i = 0; i < 4; ++i) {
        const int g0 = 2 * i;
        LOADG(wB, g0 + 1);
        COMPG(wA, g0);
        LOADG(wA, g0 + 2);
        COMPG(wB, g0 + 1);
    }
    LOADG(wB, 9);
    COMPG(wA, 8);
    COMPG(wB, 9);

#undef LOADG
#undef COMPG

    const float cost_alpha = __shfl(saved, lablen);
    if (u == 0) out[b] = -cost_alpha * LN2;   // back to natural log
}

extern "C" void kernel_launch(void* const* d_in, const int* in_sizes, int n_in,
                              void* d_out, int out_size, void* d_ws, size_t ws_size,
                              hipStream_t stream) {
    const float* acts          = (const float*)d_in[0];
    const int*   labels        = (const int*)d_in[1];
    const int*   input_lengths = (const int*)d_in[2];
    const int*   label_lengths = (const int*)d_in[3];
    float* out = (float*)d_out;

    float* lp_blank = (float*)d_ws;                          // NROWS floats
    float* lp_label = lp_blank + NROWS;                      // TB*TT*TS floats
    float* W        = lp_label + (size_t)TB * TT * TS;       // TB*NSS*9*SU floats

    rowlse_kernel<<<NROWS / 4, 256, 0, stream>>>(acts, labels, lp_blank, lp_label);
    compose_kernel<<<TB * NSS / 4, 256, 0, stream>>>(lp_blank, lp_label, W);
    scan_kernel<<<TB, 64, 0, stream>>>(W, lp_blank, lp_label,
                                       input_lengths, label_lengths, out);
}